// Round 5
// baseline (384.052 us; speedup 1.0000x reference)
//
#include <hip/hip_runtime.h>
#include <hip/hip_bf16.h>

#define BATCH 32
#define DIM 4096
#define NH 32
#define NKV 8
#define HD 128
#define CTX 4096
#define NEWT 4095
#define TCH 64               // tokens per attn block
#define NCH 64               // chunks = CTX/TCH
#define NSPLIT 32
#define KCH (DIM / NSPLIT)   // 128
#define NQKV 6144
#define SM_SCALE 0.08838834764831845f  // 1/sqrt(128)

typedef __attribute__((ext_vector_type(8))) short bf16x8;
typedef __attribute__((ext_vector_type(4))) float f32x4;

__device__ inline unsigned short f2bf(float f) {
  union { __hip_bfloat16 h; unsigned short s; } u;
  u.h = __float2bfloat16(f);
  return u.s;
}

__device__ inline bf16x8 pack8(float4 a, float4 b) {
  bf16x8 r;
  r[0] = f2bf(a.x); r[1] = f2bf(a.y); r[2] = f2bf(a.z); r[3] = f2bf(a.w);
  r[4] = f2bf(b.x); r[5] = f2bf(b.y); r[6] = f2bf(b.z); r[7] = f2bf(b.w);
  return r;
}

// ---- stage 1: qkv partial GEMM ----
__global__ __launch_bounds__(256) void gemm_qkv_part(
    const float* __restrict__ A, const float* __restrict__ wq,
    const float* __restrict__ wk, const float* __restrict__ wv,
    float* __restrict__ part) {
  int bx = blockIdx.x;
  int sy = blockIdx.y;
  int cg = bx * 256 + threadIdx.x;
  const float* W; int cw, Nw;
  if (bx < 16)      { W = wq; cw = cg;        Nw = 4096; }
  else if (bx < 20) { W = wk; cw = cg - 4096; Nw = 1024; }
  else              { W = wv; cw = cg - 5120; Nw = 1024; }
  int k0 = sy * KCH;
  float acc[BATCH];
#pragma unroll
  for (int b = 0; b < BATCH; ++b) acc[b] = 0.f;
  const float* Wp = W + (size_t)k0 * Nw + cw;
  const float* Ap = A + k0;
#pragma unroll 4
  for (int k = 0; k < KCH; ++k) {
    float wval = Wp[(size_t)k * Nw];
#pragma unroll
    for (int b = 0; b < BATCH; ++b)
      acc[b] += Ap[b * DIM + k] * wval;
  }
#pragma unroll
  for (int b = 0; b < BATCH; ++b)
    part[((size_t)sy * BATCH + b) * NQKV + cg] = acc[b];
}

// ---- stage 2: reduce partials + RoPE ----
__global__ __launch_bounds__(256) void qkv_reduce_rope(
    const float* __restrict__ part, const float* __restrict__ cos_t,
    const float* __restrict__ sin_t, float* __restrict__ q,
    float* __restrict__ k, float* __restrict__ v) {
  int idx = blockIdx.x * 256 + threadIdx.x;
  int b = idx / 3072, c2 = idx - b * 3072;
  int c = c2 * 2;
  float s0 = 0.f, s1 = 0.f;
#pragma unroll 8
  for (int s = 0; s < NSPLIT; ++s) {
    float2 pv = *(const float2*)&part[((size_t)s * BATCH + b) * NQKV + c];
    s0 += pv.x; s1 += pv.y;
  }
  if (c < 4096) {
    int p = (c & 127) >> 1;
    float cc = cos_t[p], ss = sin_t[p];
    q[b * 4096 + c]     = s0 * cc - s1 * ss;
    q[b * 4096 + c + 1] = s0 * ss + s1 * cc;
  } else if (c < 5120) {
    int c0 = c - 4096;
    int p = (c0 & 127) >> 1;
    float cc = cos_t[p], ss = sin_t[p];
    k[b * 1024 + c0]     = s0 * cc - s1 * ss;
    k[b * 1024 + c0 + 1] = s0 * ss + s1 * cc;
  } else {
    int c0 = c - 5120;
    v[b * 1024 + c0]     = s0;
    v[b * 1024 + c0 + 1] = s1;
  }
}

// ---- flash-decode: block = (b, 64-t chunk), ALL 8 kv heads, contiguous reads ----
__global__ __launch_bounds__(256, 4) void attn_kernel(
    const float* __restrict__ q,
    const float* __restrict__ kcache,
    const float* __restrict__ vcache,
    const float* __restrict__ knew,
    const float* __restrict__ vnew,
    float* __restrict__ pm, float* __restrict__ pl,
    float* __restrict__ pacc) {
  __shared__ __align__(16) unsigned short ks[16 * 1024];  // bf16 [16 t][1024 hd], XOR-swizzled
  __shared__ float sc[32 * TCH];                          // scores [32 q][64 t]
  int blk = blockIdx.x;
  int b = blk >> 6, c = blk & 63;
  int tid = threadIdx.x;
  int wave = tid >> 6, lane = tid & 63;

  // A-frags: wave owns heads 2*wave, 2*wave+1 (4 q-rows each)
  int arow = lane & 15, kgrp = lane >> 4;
  bf16x8 afrag[2][4];
#pragma unroll
  for (int hh = 0; hh < 2; ++hh)
#pragma unroll
    for (int ds = 0; ds < 4; ++ds) {
      if (arow < 4) {
        const float* qp = q + b * 4096 + ((2 * wave + hh) * 4 + arow) * 128 + ds * 32 + kgrp * 8;
        afrag[hh][ds] = pack8(*(const float4*)qp, *(const float4*)(qp + 4));
      } else {
        afrag[hh][ds] = (bf16x8)0;
      }
    }

  const float* kb = kcache + (size_t)b * (CTX * 1024);
  const float* knrow = knew + b * 1024;

  // ---- phase 1: QK^T via LDS-staged MFMA, 4 sub-tiles of 16 t ----
  for (int s = 0; s < 4; ++s) {
#pragma unroll
    for (int i0 = 0; i0 < 16; i0 += 8) {
      float4 tmp[8];
#pragma unroll
      for (int i = 0; i < 8; ++i) {
        int t = c * TCH + s * 16 + i0 + i;
        const float* src = (t < NEWT) ? (kb + (size_t)t * 1024) : knrow;
        tmp[i] = *(const float4*)(src + tid * 4);   // block-wide 4 KB contiguous
      }
#pragma unroll
      for (int i = 0; i < 8; ++i) {
        int row = i0 + i;
        union { unsigned short u[4]; uint2 v; } pk;
        pk.u[0] = f2bf(tmp[i].x); pk.u[1] = f2bf(tmp[i].y);
        pk.u[2] = f2bf(tmp[i].z); pk.u[3] = f2bf(tmp[i].w);
        int byteoff = (row * 2048 + tid * 8) ^ ((row & 7) << 4);
        *(uint2*)((char*)ks + byteoff) = pk.v;
      }
    }
    __syncthreads();
    int tcol = lane & 15;
#pragma unroll
    for (int hh = 0; hh < 2; ++hh) {
      f32x4 cacc = {0.f, 0.f, 0.f, 0.f};
#pragma unroll
      for (int ds = 0; ds < 4; ++ds) {
        int byteoff = (tcol * 2048 + ((2 * wave + hh) * 128 + ds * 32 + kgrp * 8) * 2)
                      ^ ((tcol & 7) << 4);
        bf16x8 bfrag = *(const bf16x8*)((const char*)ks + byteoff);
        cacc = __builtin_amdgcn_mfma_f32_16x16x32_bf16(afrag[hh][ds], bfrag, cacc, 0, 0, 0);
      }
      if (lane < 16) {
#pragma unroll
        for (int i = 0; i < 4; ++i)
          sc[((2 * wave + hh) * 4 + i) * TCH + s * 16 + lane] = cacc[i] * SM_SCALE;
      }
    }
    __syncthreads();
  }

  // ---- chunk softmax: thread (row=tid>>3, j=tid&7), 8 t each ----
  {
    int row = tid >> 3, j = tid & 7;
    float m = -1e30f;
#pragma unroll
    for (int i = 0; i < 8; ++i) m = fmaxf(m, sc[row * TCH + j * 8 + i]);
#pragma unroll
    for (int off = 4; off >= 1; off >>= 1) m = fmaxf(m, __shfl_xor(m, off));
    float ssum = 0.f;
#pragma unroll
    for (int i = 0; i < 8; ++i) {
      float pv = __expf(sc[row * TCH + j * 8 + i] - m);
      sc[row * TCH + j * 8 + i] = pv;
      ssum += pv;
    }
#pragma unroll
    for (int off = 4; off >= 1; off >>= 1) ssum += __shfl_xor(ssum, off);
    if (j == 0) { pm[blk * 32 + row] = m; pl[blk * 32 + row] = ssum; }
  }
  __syncthreads();

  // ---- phase 2: PV, thread = (h=tid>>5, dq=tid&31); V loads contiguous ----
  {
    int h = tid >> 5;
    float4 acc[4];
#pragma unroll
    for (int r = 0; r < 4; ++r) acc[r] = make_float4(0.f, 0.f, 0.f, 0.f);
    const float* vb = vcache + (size_t)b * (CTX * 1024);
    const float* vnrow = vnew + b * 1024;
#pragma unroll 4
    for (int t = 0; t < TCH; ++t) {
      int gt = c * TCH + t;
      const float* src = (gt < NEWT) ? (vb + (size_t)gt * 1024) : vnrow;
      float4 vv = *(const float4*)(src + tid * 4);   // block-wide 4 KB contiguous
#pragma unroll
      for (int r = 0; r < 4; ++r) {
        float p = sc[(h * 4 + r) * TCH + t];         // LDS broadcast per 32-lane group
        acc[r].x += p * vv.x;
        acc[r].y += p * vv.y;
        acc[r].z += p * vv.z;
        acc[r].w += p * vv.w;
      }
    }
    int dq = tid & 31;
#pragma unroll
    for (int r = 0; r < 4; ++r)
      *(float4*)&pacc[(size_t)blk * 4096 + (h * 4 + r) * 128 + dq * 4] = acc[r];
  }
}

// ---- combine 64 chunk partials ----
__global__ __launch_bounds__(256) void combine_kernel(
    const float* __restrict__ pm, const float* __restrict__ pl,
    const float* __restrict__ pacc, float* __restrict__ outa) {
  int idx = blockIdx.x * 256 + threadIdx.x;   // 131072 total
  int d = idx & 127, qh = (idx >> 7) & 31, b = idx >> 12;
  int base = b * 64;
  float M = -1e30f;
#pragma unroll 8
  for (int c = 0; c < NCH; ++c) M = fmaxf(M, pm[(base + c) * 32 + qh]);
  float num = 0.f, den = 0.f;
#pragma unroll 4
  for (int c = 0; c < NCH; ++c) {
    float w = __expf(pm[(base + c) * 32 + qh] - M);
    den += w * pl[(base + c) * 32 + qh];
    num += w * pacc[(size_t)(base + c) * 4096 + qh * 128 + d];
  }
  outa[b * 4096 + qh * 128 + d] = num / den;
}

// ---- wo projection ----
__global__ __launch_bounds__(256) void gemm_wo_part(
    const float* __restrict__ A, const float* __restrict__ W,
    float* __restrict__ part) {
  int c = blockIdx.x * 256 + threadIdx.x;
  int sy = blockIdx.y;
  int k0 = sy * KCH;
  float acc[BATCH];
#pragma unroll
  for (int b = 0; b < BATCH; ++b) acc[b] = 0.f;
  const float* Wp = W + (size_t)k0 * DIM + c;
  const float* Ap = A + k0;
#pragma unroll 4
  for (int k = 0; k < KCH; ++k) {
    float wval = Wp[(size_t)k * DIM];
#pragma unroll
    for (int b = 0; b < BATCH; ++b)
      acc[b] += Ap[b * DIM + k] * wval;
  }
#pragma unroll
  for (int b = 0; b < BATCH; ++b)
    part[((size_t)sy * BATCH + b) * DIM + c] = acc[b];
}

__global__ __launch_bounds__(256) void wo_reduce(
    const float* __restrict__ part, float* __restrict__ out) {
  int idx = blockIdx.x * 256 + threadIdx.x;
  int b = idx >> 11, c2 = idx & 2047;
  int c = c2 * 2;
  float s0 = 0.f, s1 = 0.f;
#pragma unroll 8
  for (int s = 0; s < NSPLIT; ++s) {
    float2 pv = *(const float2*)&part[((size_t)s * BATCH + b) * DIM + c];
    s0 += pv.x; s1 += pv.y;
  }
  out[b * DIM + c]     = s0;
  out[b * DIM + c + 1] = s1;
}

extern "C" void kernel_launch(void* const* d_in, const int* in_sizes, int n_in,
                              void* d_out, int out_size, void* d_ws, size_t ws_size,
                              hipStream_t stream) {
  const float* x  = (const float*)d_in[0];
  const float* wq = (const float*)d_in[1];
  const float* wk = (const float*)d_in[2];
  const float* wv = (const float*)d_in[3];
  const float* wo = (const float*)d_in[4];
  const float* ck = (const float*)d_in[5];
  const float* cv = (const float*)d_in[6];
  const float* fc = (const float*)d_in[7];
  const float* fs = (const float*)d_in[8];
  float* out = (float*)d_out;

  float* ws    = (float*)d_ws;
  float* ws_q  = ws;               // 131072
  float* ws_k  = ws + 131072;      // 32768
  float* ws_v  = ws + 163840;      // 32768
  float* ws_a  = ws + 196608;      // 131072
  float* pm    = ws + 327680;      // 65536
  float* pl    = ws + 393216;      // 65536
  float* pacc  = ws + 458752;      // 8388608  (2048 blk x 4096)
  float* partq = ws + 8847360;     // 6291456
  float* parto = ws + 15138816;    // 4194304
  // total ~19.3M floats ~= 77 MB

  gemm_qkv_part<<<dim3(24, NSPLIT), 256, 0, stream>>>(x, wq, wk, wv, partq);
  qkv_reduce_rope<<<384, 256, 0, stream>>>(partq, fc, fs, ws_q, ws_k, ws_v);

  attn_kernel<<<BATCH * NCH, 256, 0, stream>>>(ws_q, ck, cv, ws_k, ws_v, pm, pl, pacc);
  combine_kernel<<<512, 256, 0, stream>>>(pm, pl, pacc, ws_a);

  gemm_wo_part<<<dim3(16, NSPLIT), 256, 0, stream>>>(ws_a, wo, parto);
  wo_reduce<<<256, 256, 0, stream>>>(parto, out);
}